// Round 10
// baseline (411.856 us; speedup 1.0000x reference)
//
#include <hip/hip_runtime.h>

#define HIDDEN 51
#define LSEQ 1000
#define UNROLL 8    // steps per group (x prefetch + store granularity)

typedef _Float16 half2_t __attribute__((ext_vector_type(2)));

#if __has_builtin(__builtin_amdgcn_fdot2)
#define FDOT2(a, b, c) __builtin_amdgcn_fdot2((a), (b), (c), false)
#else
#define FDOT2(a, b, c) fmaf((float)(a).y, (float)(b).y, \
                       fmaf((float)(a).x, (float)(b).x, (c)))
#endif

// Branch-free tanh: tanh(v) = 1 - 2/(exp2(2*log2e*v)+1). Saturates to +/-1.
__device__ __forceinline__ float fast_tanh(float v) {
    float e = __builtin_amdgcn_exp2f(v * 2.885390081777927f);  // 2*log2(e)
    float r = __builtin_amdgcn_rcpf(e + 1.0f);
    return fmaf(-2.0f, r, 1.0f);
}

// One DPP-reduce level: v += dpp(v). ctrl/row_mask as template args --
// __builtin_amdgcn_update_dpp requires constant operands (R7 lesson).
template <int CTRL, int ROW_MASK>
__device__ __forceinline__ float dpp_add(float v) {
    int s = __builtin_amdgcn_update_dpp(0, __builtin_bit_cast(int, v),
                                        CTRL, ROW_MASK, 0xf, true);
    return v + __builtin_bit_cast(float, s);
}

// Full-wave sum -> lane 63 (rocPRIM gfx9 pattern). Register-only VALU ops,
// zero LDS-pipe traffic (fences below don't pin it -- not a memory op).
__device__ __forceinline__ float wave_reduce_to63(float v) {
    v = dpp_add<0x111, 0xf>(v);  // row_shr:1
    v = dpp_add<0x112, 0xf>(v);  // row_shr:2
    v = dpp_add<0x114, 0xf>(v);  // row_shr:4
    v = dpp_add<0x118, 0xf>(v);  // row_shr:8 -> lanes 15/31/47/63 = row sums
    v = dpp_add<0x142, 0xa>(v);  // row_bcast15 -> lane31+=l15, lane63+=l47
    v = dpp_add<0x143, 0xc>(v);  // row_bcast31 -> lanes 32..63 += lane31
    return v;                    // lane 63 = full sum
}

// R10 = R8 + 8-way dot-chain ILP (R9 intent) + the LDS ordering hazard
// actually closed.
// R9 post-mortem: absmax 4.56 was NOT numerics (a pure reassociation can't
// beat R6's f16-U perturbation, which only gave 0.0156) -- it was the
// __restrict__ LDS read pointer aliasing hb16. restrict + TBAA license the
// compiler to hoist the broadcast reads across the h store; wave_barrier
// is a convergence hint, NOT a memory fence. R0-R8 were silently lucky;
// R9's 8 independent chains finally motivated the hoist -> stale h.
// Fix (zero runtime cost): no restrict on the read pointer; explicit
// asm-"memory" fences bracketing the h store (mandatory ordering
// regardless of TBAA); constant-indexed register unpack of the 28 words.
// Perf theory (unchanged from R9): R6 dropped R0's 8 accumulator chains
// to 4 depth-26 chains; at 4x2cy=8cy issue/round, dot2 latency >8cy makes
// the dot phase chain-latency-bound (~312cy vs 208 ideal) -- matching the
// ~300cy/step unexplained gap. Two depth-13 chains per gate restore
// issue-bound operation.
// Trail: multi-wave (R1/R2/R3) regressed; hard fence (R5) spilled U;
// f16 U + dot2 (R6, 488->428) and x-prefetch + DPP reduce (R8, ->404) won.
__global__ __launch_bounds__(64, 1) void lstm_seq_kernel(
    const float* __restrict__ x,
    const float* __restrict__ W_w,
    const float* __restrict__ W_b,
    const float* __restrict__ U_w,
    const float* __restrict__ U_b,
    const float* __restrict__ lin_w,
    const float* __restrict__ lin_b,
    float* __restrict__ out)
{
    __shared__ __attribute__((aligned(16))) _Float16 hb16[64];  // h bcast (f16)

    const int b    = blockIdx.x;
    const int lane = threadIdx.x;        // 0..63
    const bool active = lane < HIDDEN;   // lanes 51..63 produce exact zeros
    const int m = active ? lane : 0;

    float ww[4], bbias[4];
#pragma unroll
    for (int g = 0; g < 4; ++g) {
        const int row = m + g * HIDDEN;
        ww[g]    = active ? W_w[row] : 0.f;
        bbias[g] = active ? (W_b[row] + U_b[row]) : 0.f;
    }
    const float lw = active ? lin_w[m] : 0.f;
    const float lb = lin_b[0];

    // U packed as f16 k-pairs: Up[g][j] = {U[row][2j], U[row][2j+1]}, j<26.
    // k>=51 zero-padded (matches hb16[51..63]==0 from inactive lanes).
    half2_t Up[4][26];
#pragma unroll
    for (int j = 0; j < 26; ++j) {
        const int k0 = 2 * j, k1 = 2 * j + 1;
#pragma unroll
        for (int g = 0; g < 4; ++g) {
            const int row = m + g * HIDDEN;
            half2_t u;
            u.x = (_Float16)((active && k0 < HIDDEN) ? U_w[row * HIDDEN + k0] : 0.f);
            u.y = (_Float16)((active && k1 < HIDDEN) ? U_w[row * HIDDEN + k1] : 0.f);
            Up[g][j] = u;
        }
    }

    float h = 0.f, c = 0.f;
    const float* __restrict__ xrow = x + (long)b * LSEQ;
    float* __restrict__ orow = out + (long)b * LSEQ;

    hb16[lane] = (_Float16)0.f;           // single wave: in-order LDS pipe
    __builtin_amdgcn_wave_barrier();
    asm volatile("" ::: "memory");        // init-store precedes first reads

    // NO restrict: reads must be assumed to alias the hb16 stores.
    const uint4* hbv = (const uint4*)hb16;  // 8 f16 per b128 read

    // Prologue: group 0's x resident before the loop.
    float xg[UNROLL];
#pragma unroll
    for (int s = 0; s < UNROLL; ++s) xg[s] = xrow[s];

    for (int T = 0; T < LSEQ; T += UNROLL) {
        // Prefetch NEXT group's x; consumed next iteration. Last group
        // prefetches row start (valid memory, values unused).
        const int Tn = (T + UNROLL < LSEQ) ? (T + UNROLL) : 0;
        float xn[UNROLL];
#pragma unroll
        for (int s = 0; s < UNROLL; ++s) xn[s] = xrow[Tn + s];

        float rsum[UNROLL];
#pragma unroll
        for (int s = 0; s < UNROLL; ++s) {
            // 7 same-address b128 broadcasts (conflict-free), unpacked to
            // a constant-indexed register array (28 words = k-pairs 0..27;
            // 26,27 are zero pad).
            unsigned int hw[28];
#pragma unroll
            for (int q = 0; q < 7; ++q) {
                const uint4 t = hbv[q];
                hw[4 * q + 0] = t.x;
                hw[4 * q + 1] = t.y;
                hw[4 * q + 2] = t.z;
                hw[4 * q + 3] = t.w;
            }

            // 8 independent dot2 chains: gate g x {A: pairs 0-12,
            // B: pairs 13-25}. 8 dot2/round = 16cy issue >= dot2 latency
            // -> issue-bound. A seeded with x*W + (W_b+U_b), B with 0.
            float aA[4], aB[4];
#pragma unroll
            for (int g = 0; g < 4; ++g) {
                aA[g] = fmaf(xg[s], ww[g], bbias[g]);
                aB[g] = 0.f;
            }
#pragma unroll
            for (int j = 0; j < 13; ++j) {
                const half2_t hpA = __builtin_bit_cast(half2_t, hw[j]);
                const half2_t hpB = __builtin_bit_cast(half2_t, hw[j + 13]);
#pragma unroll
                for (int g = 0; g < 4; ++g) {
                    aA[g] = FDOT2(hpA, Up[g][j],      aA[g]);
                    aB[g] = FDOT2(hpB, Up[g][j + 13], aB[g]);
                }
            }
            const float gi = aA[0] + aB[0];
            const float gf = aA[1] + aB[1];
            const float gg = aA[2] + aB[2];
            const float go = aA[3] + aB[3];

            // NOTE: faithful to reference -- no sigmoid on gates.
            c = fmaf(gf, c, gi * gg);
            h = go * fast_tanh(c);        // inactive lanes stay exactly 0

            __builtin_amdgcn_wave_barrier();
            asm volatile("" ::: "memory");    // reads above precede store
            hb16[lane] = (_Float16)h;         // 2B store; recurrence fp32
            __builtin_amdgcn_wave_barrier();
            asm volatile("" ::: "memory");    // store precedes next reads

            // Projection reduce in the broadcast-read shadow: register-only
            // DPP, free to overlap step s+1's LDS window.
            rsum[s] = wave_reduce_to63(h * lw);
        }

        if (lane == 63) {
            float4 o0 = {rsum[0] + lb, rsum[1] + lb, rsum[2] + lb, rsum[3] + lb};
            float4 o1 = {rsum[4] + lb, rsum[5] + lb, rsum[6] + lb, rsum[7] + lb};
            *(float4*)&orow[T]     = o0;   // orow 16B-aligned (b*4000 bytes)
            *(float4*)&orow[T + 4] = o1;
        }

#pragma unroll
        for (int s = 0; s < UNROLL; ++s) xg[s] = xn[s];  // rotate buffers
    }
}

extern "C" void kernel_launch(void* const* d_in, const int* in_sizes, int n_in,
                              void* d_out, int out_size, void* d_ws, size_t ws_size,
                              hipStream_t stream) {
    const float* x     = (const float*)d_in[0];
    const float* W_w   = (const float*)d_in[1];
    const float* W_b   = (const float*)d_in[2];
    const float* U_w   = (const float*)d_in[3];
    const float* U_b   = (const float*)d_in[4];
    const float* lin_w = (const float*)d_in[5];
    const float* lin_b = (const float*)d_in[6];
    // d_in[7] = future (static 0; out_size == B*LSEQ)
    float* out = (float*)d_out;

    const int B = in_sizes[0] / LSEQ;  // 1024
    lstm_seq_kernel<<<dim3(B), dim3(64), 0, stream>>>(
        x, W_w, W_b, U_w, U_b, lin_w, lin_b, out);
}

// Round 12
// 409.998 us; speedup vs baseline: 1.0045x; 1.0045x over previous
//
#include <hip/hip_runtime.h>

#define HIDDEN 51
#define LSEQ 1000
#define UNROLL 8    // steps per group (x prefetch + store granularity)

typedef _Float16 half2_t __attribute__((ext_vector_type(2)));

#if __has_builtin(__builtin_amdgcn_fdot2)
#define FDOT2(a, b, c) __builtin_amdgcn_fdot2((a), (b), (c), false)
#else
#define FDOT2(a, b, c) fmaf((float)(a).y, (float)(b).y, \
                       fmaf((float)(a).x, (float)(b).x, (c)))
#endif

// Branch-free tanh: tanh(v) = 1 - 2/(exp2(2*log2e*v)+1). Saturates to +/-1.
__device__ __forceinline__ float fast_tanh(float v) {
    float e = __builtin_amdgcn_exp2f(v * 2.885390081777927f);  // 2*log2(e)
    float r = __builtin_amdgcn_rcpf(e + 1.0f);
    return fmaf(-2.0f, r, 1.0f);
}

// One DPP-reduce level: v += dpp(v). ctrl/row_mask as template args --
// __builtin_amdgcn_update_dpp requires constant operands (R7 lesson).
template <int CTRL, int ROW_MASK>
__device__ __forceinline__ float dpp_add(float v) {
    int s = __builtin_amdgcn_update_dpp(0, __builtin_bit_cast(int, v),
                                        CTRL, ROW_MASK, 0xf, true);
    return v + __builtin_bit_cast(float, s);
}

// Full-wave sum -> lane 63 (rocPRIM gfx9 pattern). Register-only VALU ops,
// zero LDS-pipe traffic.
__device__ __forceinline__ float wave_reduce_to63(float v) {
    v = dpp_add<0x111, 0xf>(v);  // row_shr:1
    v = dpp_add<0x112, 0xf>(v);  // row_shr:2
    v = dpp_add<0x114, 0xf>(v);  // row_shr:4
    v = dpp_add<0x118, 0xf>(v);  // row_shr:8 -> lanes 15/31/47/63 = row sums
    v = dpp_add<0x142, 0xa>(v);  // row_bcast15 -> lane31+=l15, lane63+=l47
    v = dpp_add<0x143, 0xc>(v);  // row_bcast31 -> lanes 32..63 += lane31
    return v;                    // lane 63 = full sum
}

// R12 = R10 with waves_per_eu pinned to (1,1) so Up homes in arch VGPRs.
// Evidence chain:
//  - Busy-cycle audit: every round shows ~565-590cy/step busy, ~210cy
//    above ideal issue == 104 v_accvgpr_read/step (Up's 104 dwords homed
//    in AGPRs, per-use VGPR staging).
//  - R11 compile fail: gfx950 VOP3P (v_dot2) CANNOT source AGPRs --
//    the staging tax is structural GIVEN AGPR homing. Attack the homing.
//  - Why AGPR homing? Demand (~210 regs) < 256 cap, but launch_bounds'
//    min-waves only bounds BELOW; the occupancy heuristic still shrinks
//    arch-VGPR count by offloading to AGPR. Our occupancy is grid-limited
//    (1024 waves / 1024 SIMDs) -- the heuristic optimizes a dead metric.
//  - Fix: amdgpu_waves_per_eu(1,1). Max=1 kills the incentive; allocator
//    keeps Up in arch VGPRs; copies vanish. No asm, nothing else moves.
// Watch: FETCH_SIZE explosion = scratch spill (R5 signature) -> fallback
// is asm-"v" forcing. Trail: multi-wave (R1-R3) regressed; R5 spilled;
// R6 f16+dot2 win; R8 x-prefetch+DPP win; R9/R10 restrict-UB fixed.
__global__ __attribute__((amdgpu_flat_work_group_size(64, 64),
                          amdgpu_waves_per_eu(1, 1)))
void lstm_seq_kernel(
    const float* __restrict__ x,
    const float* __restrict__ W_w,
    const float* __restrict__ W_b,
    const float* __restrict__ U_w,
    const float* __restrict__ U_b,
    const float* __restrict__ lin_w,
    const float* __restrict__ lin_b,
    float* __restrict__ out)
{
    __shared__ __attribute__((aligned(16))) _Float16 hb16[64];  // h bcast (f16)

    const int b    = blockIdx.x;
    const int lane = threadIdx.x;        // 0..63
    const bool active = lane < HIDDEN;   // lanes 51..63 produce exact zeros
    const int m = active ? lane : 0;

    float ww[4], bbias[4];
#pragma unroll
    for (int g = 0; g < 4; ++g) {
        const int row = m + g * HIDDEN;
        ww[g]    = active ? W_w[row] : 0.f;
        bbias[g] = active ? (W_b[row] + U_b[row]) : 0.f;
    }
    const float lw = active ? lin_w[m] : 0.f;
    const float lb = lin_b[0];

    // U packed as f16 k-pairs: Up[g][j] = {U[row][2j], U[row][2j+1]}, j<26.
    // k>=51 zero-padded (matches hb16[51..63]==0 from inactive lanes).
    // 104 dwords; with waves_per_eu(1,1) these should home in arch VGPRs.
    half2_t Up[4][26];
#pragma unroll
    for (int j = 0; j < 26; ++j) {
        const int k0 = 2 * j, k1 = 2 * j + 1;
#pragma unroll
        for (int g = 0; g < 4; ++g) {
            const int row = m + g * HIDDEN;
            half2_t u;
            u.x = (_Float16)((active && k0 < HIDDEN) ? U_w[row * HIDDEN + k0] : 0.f);
            u.y = (_Float16)((active && k1 < HIDDEN) ? U_w[row * HIDDEN + k1] : 0.f);
            Up[g][j] = u;
        }
    }

    float h = 0.f, c = 0.f;
    const float* __restrict__ xrow = x + (long)b * LSEQ;
    float* __restrict__ orow = out + (long)b * LSEQ;

    hb16[lane] = (_Float16)0.f;           // single wave: in-order LDS pipe
    __builtin_amdgcn_wave_barrier();
    asm volatile("" ::: "memory");        // init-store precedes first reads

    // NO restrict: reads must be assumed to alias the hb16 stores (R9 bug).
    const uint4* hbv = (const uint4*)hb16;  // 8 f16 per b128 read

    // Prologue: group 0's x resident before the loop.
    float xg[UNROLL];
#pragma unroll
    for (int s = 0; s < UNROLL; ++s) xg[s] = xrow[s];

    for (int T = 0; T < LSEQ; T += UNROLL) {
        // Prefetch NEXT group's x; consumed next iteration. Last group
        // prefetches row start (valid memory, values unused).
        const int Tn = (T + UNROLL < LSEQ) ? (T + UNROLL) : 0;
        float xn[UNROLL];
#pragma unroll
        for (int s = 0; s < UNROLL; ++s) xn[s] = xrow[Tn + s];

        float rsum[UNROLL];
#pragma unroll
        for (int s = 0; s < UNROLL; ++s) {
            // 7 same-address b128 broadcasts (conflict-free), unpacked to
            // a constant-indexed register array (28 words = k-pairs 0..27;
            // 26,27 are zero pad).
            unsigned int hw[28];
#pragma unroll
            for (int q = 0; q < 7; ++q) {
                const uint4 t = hbv[q];
                hw[4 * q + 0] = t.x;
                hw[4 * q + 1] = t.y;
                hw[4 * q + 2] = t.z;
                hw[4 * q + 3] = t.w;
            }

            // 8 independent dot2 chains: gate g x {A: pairs 0-12,
            // B: pairs 13-25}. A seeded with x*W + (W_b+U_b), B with 0.
            float aA[4], aB[4];
#pragma unroll
            for (int g = 0; g < 4; ++g) {
                aA[g] = fmaf(xg[s], ww[g], bbias[g]);
                aB[g] = 0.f;
            }
#pragma unroll
            for (int j = 0; j < 13; ++j) {
                const half2_t hpA = __builtin_bit_cast(half2_t, hw[j]);
                const half2_t hpB = __builtin_bit_cast(half2_t, hw[j + 13]);
#pragma unroll
                for (int g = 0; g < 4; ++g) {
                    aA[g] = FDOT2(hpA, Up[g][j],      aA[g]);
                    aB[g] = FDOT2(hpB, Up[g][j + 13], aB[g]);
                }
            }
            const float gi = aA[0] + aB[0];
            const float gf = aA[1] + aB[1];
            const float gg = aA[2] + aB[2];
            const float go = aA[3] + aB[3];

            // NOTE: faithful to reference -- no sigmoid on gates.
            c = fmaf(gf, c, gi * gg);
            h = go * fast_tanh(c);        // inactive lanes stay exactly 0

            __builtin_amdgcn_wave_barrier();
            asm volatile("" ::: "memory");    // reads above precede store
            hb16[lane] = (_Float16)h;         // 2B store; recurrence fp32
            __builtin_amdgcn_wave_barrier();
            asm volatile("" ::: "memory");    // store precedes next reads

            // Projection reduce in the broadcast-read shadow: register-only
            // DPP, free to overlap step s+1's LDS window.
            rsum[s] = wave_reduce_to63(h * lw);
        }

        if (lane == 63) {
            float4 o0 = {rsum[0] + lb, rsum[1] + lb, rsum[2] + lb, rsum[3] + lb};
            float4 o1 = {rsum[4] + lb, rsum[5] + lb, rsum[6] + lb, rsum[7] + lb};
            *(float4*)&orow[T]     = o0;   // orow 16B-aligned (b*4000 bytes)
            *(float4*)&orow[T + 4] = o1;
        }

#pragma unroll
        for (int s = 0; s < UNROLL; ++s) xg[s] = xn[s];  // rotate buffers
    }
}

extern "C" void kernel_launch(void* const* d_in, const int* in_sizes, int n_in,
                              void* d_out, int out_size, void* d_ws, size_t ws_size,
                              hipStream_t stream) {
    const float* x     = (const float*)d_in[0];
    const float* W_w   = (const float*)d_in[1];
    const float* W_b   = (const float*)d_in[2];
    const float* U_w   = (const float*)d_in[3];
    const float* U_b   = (const float*)d_in[4];
    const float* lin_w = (const float*)d_in[5];
    const float* lin_b = (const float*)d_in[6];
    // d_in[7] = future (static 0; out_size == B*LSEQ)
    float* out = (float*)d_out;

    const int B = in_sizes[0] / LSEQ;  // 1024
    lstm_seq_kernel<<<dim3(B), dim3(64), 0, stream>>>(
        x, W_w, W_b, U_w, U_b, lin_w, lin_b, out);
}